// Round 2
// baseline (1208.191 us; speedup 1.0000x reference)
//
#include <hip/hip_runtime.h>
#include <hip/hip_bf16.h>

// EdgePredictorGNN: 2-layer GCN + edge MLP.
// N=50000 nodes, in_c=128, hid=64, out_c=16, E=800000 edges.

#define IN_C 128
#define HID 64
#define OUT_C 16

__device__ __forceinline__ float rlanef(float v, int l) {
    return __uint_as_float(__builtin_amdgcn_readlane(__float_as_uint(v), l));
}

// ---------------- CSR build ----------------

__global__ void k_init_cnt(int* __restrict__ cnt, int n) {
    int i = blockIdx.x * blockDim.x + threadIdx.x;
    if (i < n) cnt[i] = 0;
}

__global__ void k_count(const int* __restrict__ ei, int* __restrict__ cnt, int e) {
    int i = blockIdx.x * blockDim.x + threadIdx.x;
    if (i < e) atomicAdd(&cnt[ei[e + i]], 1);   // dst = ei[1][i]
}

__global__ __launch_bounds__(1024) void k_scan1(const int* __restrict__ cnt,
                                                int* __restrict__ tmp,
                                                int* __restrict__ bsum, int n) {
    __shared__ int s[1024];
    int i = blockIdx.x * 1024 + threadIdx.x;
    int v = (i < n) ? cnt[i] : 0;
    s[threadIdx.x] = v;
    __syncthreads();
    for (int off = 1; off < 1024; off <<= 1) {
        int add = (threadIdx.x >= off) ? s[threadIdx.x - off] : 0;
        __syncthreads();
        s[threadIdx.x] += add;
        __syncthreads();
    }
    if (i < n) tmp[i] = s[threadIdx.x];
    if (threadIdx.x == 1023) bsum[blockIdx.x] = s[1023];
}

__global__ void k_scan2(int* __restrict__ bsum, int nb) {
    if (blockIdx.x == 0 && threadIdx.x == 0) {
        int run = 0;
        for (int b = 0; b < nb; ++b) { int v = bsum[b]; bsum[b] = run; run += v; }
    }
}

__global__ void k_scan3(const int* __restrict__ cnt, const int* __restrict__ tmp,
                        const int* __restrict__ bsum, int* __restrict__ rowptr,
                        int* __restrict__ cur, float* __restrict__ dinv, int n, int e) {
    int i = blockIdx.x * blockDim.x + threadIdx.x;
    if (i < n) {
        int excl = tmp[i] - cnt[i] + bsum[i >> 10];
        rowptr[i] = excl;
        cur[i] = excl;
        dinv[i] = 1.0f / sqrtf((float)(cnt[i] + 1));  // +1 self loop
        if (i == 0) rowptr[n] = e;
    }
}

__global__ void k_scatter(const int* __restrict__ ei, int* __restrict__ cur,
                          int* __restrict__ csrc, int e) {
    int i = blockIdx.x * blockDim.x + threadIdx.x;
    if (i < e) {
        int s = ei[i];
        int d = ei[e + i];
        int p = atomicAdd(&cur[d], 1);
        csrc[p] = s;
    }
}

// ---------------- node GEMM: T = (A @ W) * dinv[row]  (W is [K,64]) ----------------
// 4 waves/block; lane = output col; weights stationary in VGPRs;
// A-row loaded per-lane (coalesced), broadcast via v_readlane.

template <int K>
__global__ __launch_bounds__(256) void k_gemm_node(const float* __restrict__ A,
                                                   const float* __restrict__ W,
                                                   const float* __restrict__ dinv,
                                                   float* __restrict__ T,
                                                   int n, int npw) {
    int lane = threadIdx.x & 63;
    int w = threadIdx.x >> 6;
    float wr[K];
#pragma unroll
    for (int k = 0; k < K; ++k) wr[k] = W[k * 64 + lane];
    int gw = blockIdx.x * 4 + w;
    int n0 = gw * npw;
    int n1 = n0 + npw; if (n1 > n) n1 = n;
#pragma unroll 1
    for (int i = n0; i < n1; ++i) {
        float a0 = A[(size_t)i * K + lane];
        float a1 = 0.f;
        if (K == 128) a1 = A[(size_t)i * K + 64 + lane];
        float acc = 0.f;
#pragma unroll
        for (int k = 0; k < 64; ++k) acc = fmaf(rlanef(a0, k), wr[k], acc);
        if (K == 128) {
#pragma unroll
            for (int k = 0; k < 64; ++k) acc = fmaf(rlanef(a1, k), wr[64 + k], acc);
        }
        T[(size_t)i * 64 + lane] = acc * dinv[i];
    }
}

// ---------------- GCN aggregation ----------------
// T rows are pre-scaled by dinv[src]. h[n] = relu(b + dinv[n] * sum_{s in {n} u N(n)} T[s])
__global__ __launch_bounds__(256) void k_agg(const float* __restrict__ T,
                                             const int* __restrict__ rowptr,
                                             const int* __restrict__ csrc,
                                             const float* __restrict__ dinv,
                                             const float* __restrict__ bias,
                                             float* __restrict__ H, int n) {
    int lane = threadIdx.x & 63;
    int w = threadIdx.x >> 6;
    int nid = blockIdx.x * 4 + w;
    if (nid >= n) return;
    float dn = dinv[nid];
    float acc = T[(size_t)nid * 64 + lane];   // self loop (pre-scaled)
    int r0 = rowptr[nid], r1 = rowptr[nid + 1];
#pragma unroll 1
    for (int p0 = r0; p0 < r1; p0 += 64) {
        int m = r1 - p0; if (m > 64) m = 64;
        int sv = (lane < m) ? csrc[p0 + lane] : 0;
        if (m == 64) {
#pragma unroll
            for (int i = 0; i < 64; ++i) {
                int s = __builtin_amdgcn_readlane(sv, i);
                acc += T[(size_t)s * 64 + lane];
            }
        } else {
#pragma unroll 1
            for (int i = 0; i < m; ++i) {
                int s = __builtin_amdgcn_readlane(sv, i);
                acc += T[(size_t)s * 64 + lane];
            }
        }
    }
    H[(size_t)nid * 64 + lane] = fmaxf(fmaf(dn, acc, bias[lane]), 0.f);
}

// ---------------- edge MLP ----------------
// 256 threads (4 waves), 64 edges/block.
// Phase A: coalesced float4 gather of h[r],h[c] into LDS.
// Phase B (stage 1): wave w owns edges w*16..+15; lane = z-col; Wm1 in VGPRs;
//                    h read as uniform ds_read_b128 broadcasts. z -> LDS (pitch 65).
// Stage 2: lane = (edge,out-quad); z from LDS, Wm2 from LDS; coalesced float4 out.
#define EB 64
__global__ __launch_bounds__(256) void k_mlp(const float* __restrict__ H,
                                             const int* __restrict__ ei,
                                             const float* __restrict__ Wm1,
                                             const float* __restrict__ bm1,
                                             const float* __restrict__ Wm2,
                                             const float* __restrict__ bm2,
                                             float* __restrict__ out,
                                             int e) {
    __shared__ float4 hbuf4[EB * 32];     // 64 edges x 128 floats (hr | hc), 32 KB
    __shared__ float  zb[EB * 65];        // 16.6 KB
    __shared__ float4 wm2s4[256];         // 64x16 Wm2, 4 KB
    __shared__ int    sidx[2 * EB];

    int t = threadIdx.x;
    int lane = t & 63;
    int w = t >> 6;
    int e0 = blockIdx.x * EB;

    // stationary Wm1 (lane = col)
    float w1a[64], w1b[64];
#pragma unroll
    for (int k = 0; k < 64; ++k) w1a[k] = Wm1[k * 64 + lane];
#pragma unroll
    for (int k = 0; k < 64; ++k) w1b[k] = Wm1[(64 + k) * 64 + lane];
    float bz = bm1[lane];

    if (t < 128) {
        int eid = e0 + (t & 63);
        int is_c = t >> 6;
        sidx[t] = (eid < e) ? ei[is_c * e + eid] : 0;
    }
    wm2s4[t] = ((const float4*)Wm2)[t];
    __syncthreads();

    // Phase A: gather. 2048 float4 slots, 8 per thread, coalesced per half-row.
#pragma unroll
    for (int rep = 0; rep < 8; ++rep) {
        int li = rep * 256 + t;
        int edge = li >> 5;
        int slot = li & 31;
        int half = slot >> 4;
        int k4 = slot & 15;
        int row = sidx[half * EB + edge];
        hbuf4[li] = ((const float4*)(H + (size_t)row * 64))[k4];
    }
    __syncthreads();

    // Stage 1
#pragma unroll 1
    for (int ee = 0; ee < 16; ++ee) {
        int edge = w * 16 + ee;
        const float4* hp = hbuf4 + edge * 32;
        float acc = bz;
#pragma unroll
        for (int k4 = 0; k4 < 16; ++k4) {
            float4 hv = hp[k4];
            acc = fmaf(hv.x, w1a[k4 * 4 + 0], acc);
            acc = fmaf(hv.y, w1a[k4 * 4 + 1], acc);
            acc = fmaf(hv.z, w1a[k4 * 4 + 2], acc);
            acc = fmaf(hv.w, w1a[k4 * 4 + 3], acc);
        }
#pragma unroll
        for (int k4 = 0; k4 < 16; ++k4) {
            float4 hv = hp[16 + k4];
            acc = fmaf(hv.x, w1b[k4 * 4 + 0], acc);
            acc = fmaf(hv.y, w1b[k4 * 4 + 1], acc);
            acc = fmaf(hv.z, w1b[k4 * 4 + 2], acc);
            acc = fmaf(hv.w, w1b[k4 * 4 + 3], acc);
        }
        zb[edge * 65 + lane] = fmaxf(acc, 0.f);
    }
    __syncthreads();

    // Stage 2: 64 lanes = 16 edges x 4 output-quads (per wave, own edges only)
    int edge = w * 16 + (lane >> 2);
    int i4 = lane & 3;
    float4 o = ((const float4*)bm2)[i4];
    const float* zrow = zb + edge * 65;
#pragma unroll
    for (int j = 0; j < 64; ++j) {
        float zv = zrow[j];
        float4 wv = wm2s4[j * 4 + i4];
        o.x = fmaf(zv, wv.x, o.x);
        o.y = fmaf(zv, wv.y, o.y);
        o.z = fmaf(zv, wv.z, o.z);
        o.w = fmaf(zv, wv.w, o.w);
    }
    int eid = e0 + edge;
    if (eid < e) ((float4*)out)[(size_t)eid * 4 + i4] = o;
}

// ---------------- launch ----------------

extern "C" void kernel_launch(void* const* d_in, const int* in_sizes, int n_in,
                              void* d_out, int out_size, void* d_ws, size_t ws_size,
                              hipStream_t stream) {
    const float* x   = (const float*)d_in[0];
    const int*   ei  = (const int*)d_in[1];
    const float* W1  = (const float*)d_in[2];
    const float* b1  = (const float*)d_in[3];
    const float* W2  = (const float*)d_in[4];
    const float* b2  = (const float*)d_in[5];
    const float* Wm1 = (const float*)d_in[6];
    const float* bm1 = (const float*)d_in[7];
    const float* Wm2 = (const float*)d_in[8];
    const float* bm2 = (const float*)d_in[9];
    float* out = (float*)d_out;

    int n = in_sizes[0] / IN_C;       // 50000
    int e = in_sizes[1] / 2;          // 800000

    // workspace layout (all offsets kept 16B-aligned)
    char* w = (char*)d_ws;
    int* cnt    = (int*)w;                 w += (size_t)n * 4;
    int* tmp    = (int*)w;                 w += (size_t)n * 4;
    int* bsum   = (int*)w;                 w += 256 * 4;
    int* rowptr = (int*)w;                 w += (size_t)(n + 4) * 4;
    int* cur    = (int*)w;                 w += (size_t)n * 4;
    float* dinv = (float*)w;               w += (size_t)n * 4;
    int* csrc   = (int*)w;                 w += (size_t)e * 4;
    float* t    = (float*)w;               w += (size_t)n * HID * 4;
    float* h1   = (float*)w;               w += (size_t)n * HID * 4;
    float* h2   = (float*)w;               w += (size_t)n * HID * 4;

    int nb_n256 = (n + 255) / 256;
    int nb_e256 = (e + 255) / 256;
    int nb_scan = (n + 1023) / 1024;

    k_init_cnt<<<nb_n256, 256, 0, stream>>>(cnt, n);
    k_count<<<nb_e256, 256, 0, stream>>>(ei, cnt, e);
    k_scan1<<<nb_scan, 1024, 0, stream>>>(cnt, tmp, bsum, n);
    k_scan2<<<1, 64, 0, stream>>>(bsum, nb_scan);
    k_scan3<<<nb_n256, 256, 0, stream>>>(cnt, tmp, bsum, rowptr, cur, dinv, n, e);
    k_scatter<<<nb_e256, 256, 0, stream>>>(ei, cur, csrc, e);

    const int NPW = 8;                               // nodes per wave
    int nwaves = (n + NPW - 1) / NPW;
    int nb_gemm = (nwaves + 3) / 4;
    int nb_agg = (n + 3) / 4;
    // layer 1
    k_gemm_node<IN_C><<<nb_gemm, 256, 0, stream>>>(x, W1, dinv, t, n, NPW);
    k_agg<<<nb_agg, 256, 0, stream>>>(t, rowptr, csrc, dinv, b1, h1, n);
    // layer 2
    k_gemm_node<HID><<<nb_gemm, 256, 0, stream>>>(h1, W2, dinv, t, n, NPW);
    k_agg<<<nb_agg, 256, 0, stream>>>(t, rowptr, csrc, dinv, b2, h2, n);
    // edge MLP
    int nb_mlp = (e + EB - 1) / EB;
    k_mlp<<<nb_mlp, 256, 0, stream>>>(h2, ei, Wm1, bm1, Wm2, bm2, out, e);
}

// Round 3
// 787.633 us; speedup vs baseline: 1.5340x; 1.5340x over previous
//
#include <hip/hip_runtime.h>
#include <hip/hip_bf16.h>

// EdgePredictorGNN: 2-layer GCN + edge MLP.
// N=50000 nodes, in_c=128, hid=64, out_c=16, E=800000 edges.

#define IN_C 128
#define HID 64
#define OUT_C 16

__device__ __forceinline__ float rlanef(float v, int l) {
    return __uint_as_float(__builtin_amdgcn_readlane(__float_as_uint(v), l));
}

// ---------------- CSR build ----------------

__global__ void k_init_cnt(int* __restrict__ cnt, int n) {
    int i = blockIdx.x * blockDim.x + threadIdx.x;
    if (i < n) cnt[i] = 0;
}

__global__ void k_count(const int* __restrict__ ei, int* __restrict__ cnt, int e) {
    int i = blockIdx.x * blockDim.x + threadIdx.x;
    if (i < e) atomicAdd(&cnt[ei[e + i]], 1);   // dst = ei[1][i]
}

__global__ __launch_bounds__(1024) void k_scan1(const int* __restrict__ cnt,
                                                int* __restrict__ tmp,
                                                int* __restrict__ bsum, int n) {
    __shared__ int s[1024];
    int i = blockIdx.x * 1024 + threadIdx.x;
    int v = (i < n) ? cnt[i] : 0;
    s[threadIdx.x] = v;
    __syncthreads();
    for (int off = 1; off < 1024; off <<= 1) {
        int add = (threadIdx.x >= off) ? s[threadIdx.x - off] : 0;
        __syncthreads();
        s[threadIdx.x] += add;
        __syncthreads();
    }
    if (i < n) tmp[i] = s[threadIdx.x];
    if (threadIdx.x == 1023) bsum[blockIdx.x] = s[1023];
}

__global__ void k_scan2(int* __restrict__ bsum, int nb) {
    if (blockIdx.x == 0 && threadIdx.x == 0) {
        int run = 0;
        for (int b = 0; b < nb; ++b) { int v = bsum[b]; bsum[b] = run; run += v; }
    }
}

__global__ void k_scan3(const int* __restrict__ cnt, const int* __restrict__ tmp,
                        const int* __restrict__ bsum, int* __restrict__ rowptr,
                        int* __restrict__ cur, float* __restrict__ dinv, int n, int e) {
    int i = blockIdx.x * blockDim.x + threadIdx.x;
    if (i < n) {
        int excl = tmp[i] - cnt[i] + bsum[i >> 10];
        rowptr[i] = excl;
        cur[i] = excl;
        dinv[i] = 1.0f / sqrtf((float)(cnt[i] + 1));  // +1 self loop
        if (i == 0) rowptr[n] = e;
    }
}

__global__ void k_scatter(const int* __restrict__ ei, int* __restrict__ cur,
                          int* __restrict__ csrc, int e) {
    int i = blockIdx.x * blockDim.x + threadIdx.x;
    if (i < e) {
        int s = ei[i];
        int d = ei[e + i];
        int p = atomicAdd(&cur[d], 1);
        csrc[p] = s;
    }
}

// transpose Wm1 [128][64] -> Wt [64][128]
__global__ void k_transpose(const float* __restrict__ Wm1, float* __restrict__ Wt) {
    int t = blockIdx.x * 256 + threadIdx.x;
    if (t < 128 * 64) {
        int k = t >> 6, j = t & 63;
        Wt[j * 128 + k] = Wm1[t];
    }
}

// ---------------- node GEMM: T = (A @ W) * dinv[row]  (W is [K,64]) ----------------

template <int K>
__global__ __launch_bounds__(256) void k_gemm_node(const float* __restrict__ A,
                                                   const float* __restrict__ W,
                                                   const float* __restrict__ dinv,
                                                   float* __restrict__ T,
                                                   int n, int npw) {
    int lane = threadIdx.x & 63;
    int w = threadIdx.x >> 6;
    float wr[K];
#pragma unroll
    for (int k = 0; k < K; ++k) wr[k] = W[k * 64 + lane];
    int gw = blockIdx.x * 4 + w;
    int n0 = gw * npw;
    int n1 = n0 + npw; if (n1 > n) n1 = n;
#pragma unroll 1
    for (int i = n0; i < n1; ++i) {
        float a0 = A[(size_t)i * K + lane];
        float a1 = 0.f;
        if (K == 128) a1 = A[(size_t)i * K + 64 + lane];
        float acc = 0.f;
#pragma unroll
        for (int k = 0; k < 64; ++k) acc = fmaf(rlanef(a0, k), wr[k], acc);
        if (K == 128) {
#pragma unroll
            for (int k = 0; k < 64; ++k) acc = fmaf(rlanef(a1, k), wr[64 + k], acc);
        }
        T[(size_t)i * 64 + lane] = acc * dinv[i];
    }
}

// ---------------- GCN aggregation ----------------
__global__ __launch_bounds__(256) void k_agg(const float* __restrict__ T,
                                             const int* __restrict__ rowptr,
                                             const int* __restrict__ csrc,
                                             const float* __restrict__ dinv,
                                             const float* __restrict__ bias,
                                             float* __restrict__ H, int n) {
    int lane = threadIdx.x & 63;
    int w = threadIdx.x >> 6;
    int nid = blockIdx.x * 4 + w;
    if (nid >= n) return;
    float dn = dinv[nid];
    float acc = T[(size_t)nid * 64 + lane];   // self loop (pre-scaled)
    int r0 = rowptr[nid], r1 = rowptr[nid + 1];
#pragma unroll 1
    for (int p0 = r0; p0 < r1; p0 += 64) {
        int m = r1 - p0; if (m > 64) m = 64;
        int sv = (lane < m) ? csrc[p0 + lane] : 0;
        if (m == 64) {
#pragma unroll
            for (int i = 0; i < 64; ++i) {
                int s = __builtin_amdgcn_readlane(sv, i);
                acc += T[(size_t)s * 64 + lane];
            }
        } else {
#pragma unroll 1
            for (int i = 0; i < m; ++i) {
                int s = __builtin_amdgcn_readlane(sv, i);
                acc += T[(size_t)s * 64 + lane];
            }
        }
    }
    H[(size_t)nid * 64 + lane] = fmaxf(fmaf(dn, acc, bias[lane]), 0.f);
}

// ---------------- edge MLP ----------------
// lane = edge (64 edges/wave, 1 wave/block).
// h[r]||h[c] in 128 VGPRs/lane (independent float4 gathers).
// Stage 1: cols in groups of 4 -> ILP 4; Wm1^T rows read wave-uniform (s_load).
// z -> LDS [col][edge] (conflict-free). Stage 2: 16 accumulators, Wm2 uniform.
__global__ __launch_bounds__(64, 3) void k_mlp(const float* __restrict__ H,
                                               const int* __restrict__ ei,
                                               const float* __restrict__ Wt,   // [64][128]
                                               const float* __restrict__ bm1,
                                               const float* __restrict__ Wm2,  // [64][16]
                                               const float* __restrict__ bm2,
                                               float* __restrict__ out,
                                               int e) {
    __shared__ float zb[64 * 64];   // [col][edge], 16 KB
    int lane = threadIdx.x;
    int eid = blockIdx.x * 64 + lane;
    bool ok = eid < e;
    int r = ok ? ei[eid] : 0;
    int c = ok ? ei[e + eid] : 0;

    float h[128];
    const float4* hr = (const float4*)(H + (size_t)r * 64);
    const float4* hc = (const float4*)(H + (size_t)c * 64);
#pragma unroll
    for (int q = 0; q < 16; ++q) {
        float4 v = hr[q];
        h[q * 4 + 0] = v.x; h[q * 4 + 1] = v.y; h[q * 4 + 2] = v.z; h[q * 4 + 3] = v.w;
    }
#pragma unroll
    for (int q = 0; q < 16; ++q) {
        float4 v = hc[q];
        h[64 + q * 4 + 0] = v.x; h[64 + q * 4 + 1] = v.y; h[64 + q * 4 + 2] = v.z; h[64 + q * 4 + 3] = v.w;
    }

    // Stage 1: z[j] = relu(bm1[j] + sum_k h[k] * Wt[j][k]); 4 cols at a time.
#pragma unroll 1
    for (int j0 = 0; j0 < 64; j0 += 4) {
        const float* w0 = Wt + (size_t)(j0 + 0) * 128;
        const float* w1 = Wt + (size_t)(j0 + 1) * 128;
        const float* w2 = Wt + (size_t)(j0 + 2) * 128;
        const float* w3 = Wt + (size_t)(j0 + 3) * 128;
        float a0 = bm1[j0 + 0];
        float a1 = bm1[j0 + 1];
        float a2 = bm1[j0 + 2];
        float a3 = bm1[j0 + 3];
#pragma unroll
        for (int k = 0; k < 128; ++k) {
            float hv = h[k];
            a0 = fmaf(hv, w0[k], a0);
            a1 = fmaf(hv, w1[k], a1);
            a2 = fmaf(hv, w2[k], a2);
            a3 = fmaf(hv, w3[k], a3);
        }
        zb[(j0 + 0) * 64 + lane] = fmaxf(a0, 0.f);
        zb[(j0 + 1) * 64 + lane] = fmaxf(a1, 0.f);
        zb[(j0 + 2) * 64 + lane] = fmaxf(a2, 0.f);
        zb[(j0 + 3) * 64 + lane] = fmaxf(a3, 0.f);
    }

    // Stage 2: out[eid][i] = bm2[i] + sum_j z[j] * Wm2[j][i]  (single wave: no barrier)
    float o[16];
#pragma unroll
    for (int i = 0; i < 16; ++i) o[i] = bm2[i];
#pragma unroll 4
    for (int j = 0; j < 64; ++j) {
        float zv = zb[j * 64 + lane];
#pragma unroll
        for (int i = 0; i < 16; ++i) o[i] = fmaf(zv, Wm2[j * 16 + i], o[i]);
    }
    if (ok) {
        float4* op = (float4*)(out + (size_t)eid * 16);
        op[0] = make_float4(o[0], o[1], o[2], o[3]);
        op[1] = make_float4(o[4], o[5], o[6], o[7]);
        op[2] = make_float4(o[8], o[9], o[10], o[11]);
        op[3] = make_float4(o[12], o[13], o[14], o[15]);
    }
}

// ---------------- launch ----------------

extern "C" void kernel_launch(void* const* d_in, const int* in_sizes, int n_in,
                              void* d_out, int out_size, void* d_ws, size_t ws_size,
                              hipStream_t stream) {
    const float* x   = (const float*)d_in[0];
    const int*   ei  = (const int*)d_in[1];
    const float* W1  = (const float*)d_in[2];
    const float* b1  = (const float*)d_in[3];
    const float* W2  = (const float*)d_in[4];
    const float* b2  = (const float*)d_in[5];
    const float* Wm1 = (const float*)d_in[6];
    const float* bm1 = (const float*)d_in[7];
    const float* Wm2 = (const float*)d_in[8];
    const float* bm2 = (const float*)d_in[9];
    float* out = (float*)d_out;

    int n = in_sizes[0] / IN_C;       // 50000
    int e = in_sizes[1] / 2;          // 800000

    // workspace layout (all offsets kept 16B-aligned)
    char* w = (char*)d_ws;
    int* cnt    = (int*)w;                 w += (size_t)n * 4;
    int* tmp    = (int*)w;                 w += (size_t)n * 4;
    int* bsum   = (int*)w;                 w += 256 * 4;
    int* rowptr = (int*)w;                 w += (size_t)(n + 4) * 4;
    int* cur    = (int*)w;                 w += (size_t)n * 4;
    float* dinv = (float*)w;               w += (size_t)n * 4;
    int* csrc   = (int*)w;                 w += (size_t)e * 4;
    float* wt   = (float*)w;               w += (size_t)64 * 128 * 4;
    float* t    = (float*)w;               w += (size_t)n * HID * 4;
    float* h1   = (float*)w;               w += (size_t)n * HID * 4;
    float* h2   = (float*)w;               w += (size_t)n * HID * 4;

    int nb_n256 = (n + 255) / 256;
    int nb_e256 = (e + 255) / 256;
    int nb_scan = (n + 1023) / 1024;

    k_init_cnt<<<nb_n256, 256, 0, stream>>>(cnt, n);
    k_count<<<nb_e256, 256, 0, stream>>>(ei, cnt, e);
    k_scan1<<<nb_scan, 1024, 0, stream>>>(cnt, tmp, bsum, n);
    k_scan2<<<1, 64, 0, stream>>>(bsum, nb_scan);
    k_scan3<<<nb_n256, 256, 0, stream>>>(cnt, tmp, bsum, rowptr, cur, dinv, n, e);
    k_scatter<<<nb_e256, 256, 0, stream>>>(ei, cur, csrc, e);
    k_transpose<<<32, 256, 0, stream>>>(Wm1, wt);

    const int NPW = 8;                               // nodes per wave
    int nwaves = (n + NPW - 1) / NPW;
    int nb_gemm = (nwaves + 3) / 4;
    int nb_agg = (n + 3) / 4;
    // layer 1
    k_gemm_node<IN_C><<<nb_gemm, 256, 0, stream>>>(x, W1, dinv, t, n, NPW);
    k_agg<<<nb_agg, 256, 0, stream>>>(t, rowptr, csrc, dinv, b1, h1, n);
    // layer 2
    k_gemm_node<HID><<<nb_gemm, 256, 0, stream>>>(h1, W2, dinv, t, n, NPW);
    k_agg<<<nb_agg, 256, 0, stream>>>(t, rowptr, csrc, dinv, b2, h2, n);
    // edge MLP
    int nb_mlp = (e + 63) / 64;
    k_mlp<<<nb_mlp, 64, 0, stream>>>(h2, ei, wt, bm1, Wm2, bm2, out, e);
}

// Round 4
// 466.797 us; speedup vs baseline: 2.5883x; 1.6873x over previous
//
#include <hip/hip_runtime.h>
#include <hip/hip_bf16.h>

// EdgePredictorGNN: 2-layer GCN + edge MLP.
// N=50000 nodes, in_c=128, hid=64, out_c=16, E=800000 edges.

#define IN_C 128
#define HID 64
#define OUT_C 16

__device__ __forceinline__ float rlanef(float v, int l) {
    return __uint_as_float(__builtin_amdgcn_readlane(__float_as_uint(v), l));
}

// ---------------- CSR build ----------------

__global__ void k_init_cnt(int* __restrict__ cnt, int n) {
    int i = blockIdx.x * blockDim.x + threadIdx.x;
    if (i < n) cnt[i] = 0;
}

__global__ void k_count(const int* __restrict__ ei, int* __restrict__ cnt, int e) {
    int i = blockIdx.x * blockDim.x + threadIdx.x;
    if (i < e) atomicAdd(&cnt[ei[e + i]], 1);   // dst = ei[1][i]
}

__global__ __launch_bounds__(1024) void k_scan1(const int* __restrict__ cnt,
                                                int* __restrict__ tmp,
                                                int* __restrict__ bsum, int n) {
    __shared__ int s[1024];
    int i = blockIdx.x * 1024 + threadIdx.x;
    int v = (i < n) ? cnt[i] : 0;
    s[threadIdx.x] = v;
    __syncthreads();
    for (int off = 1; off < 1024; off <<= 1) {
        int add = (threadIdx.x >= off) ? s[threadIdx.x - off] : 0;
        __syncthreads();
        s[threadIdx.x] += add;
        __syncthreads();
    }
    if (i < n) tmp[i] = s[threadIdx.x];
    if (threadIdx.x == 1023) bsum[blockIdx.x] = s[1023];
}

__global__ void k_scan2(int* __restrict__ bsum, int nb) {
    if (blockIdx.x == 0 && threadIdx.x == 0) {
        int run = 0;
        for (int b = 0; b < nb; ++b) { int v = bsum[b]; bsum[b] = run; run += v; }
    }
}

__global__ void k_scan3(const int* __restrict__ cnt, const int* __restrict__ tmp,
                        const int* __restrict__ bsum, int* __restrict__ rowptr,
                        int* __restrict__ cur, float* __restrict__ dinv, int n, int e) {
    int i = blockIdx.x * blockDim.x + threadIdx.x;
    if (i < n) {
        int excl = tmp[i] - cnt[i] + bsum[i >> 10];
        rowptr[i] = excl;
        cur[i] = excl;
        dinv[i] = 1.0f / sqrtf((float)(cnt[i] + 1));  // +1 self loop
        if (i == 0) rowptr[n] = e;
    }
}

__global__ void k_scatter(const int* __restrict__ ei, int* __restrict__ cur,
                          int* __restrict__ csrc, int e) {
    int i = blockIdx.x * blockDim.x + threadIdx.x;
    if (i < e) {
        int s = ei[i];
        int d = ei[e + i];
        int p = atomicAdd(&cur[d], 1);
        csrc[p] = s;
    }
}

// ---------------- node GEMM: T = (A @ W) * dinv[row]  (W is [K,64]) ----------------

template <int K>
__global__ __launch_bounds__(256) void k_gemm_node(const float* __restrict__ A,
                                                   const float* __restrict__ W,
                                                   const float* __restrict__ dinv,
                                                   float* __restrict__ T,
                                                   int n, int npw) {
    int lane = threadIdx.x & 63;
    int w = threadIdx.x >> 6;
    float wr[K];
#pragma unroll
    for (int k = 0; k < K; ++k) wr[k] = W[k * 64 + lane];
    int gw = blockIdx.x * 4 + w;
    int n0 = gw * npw;
    int n1 = n0 + npw; if (n1 > n) n1 = n;
#pragma unroll 1
    for (int i = n0; i < n1; ++i) {
        float a0 = A[(size_t)i * K + lane];
        float a1 = 0.f;
        if (K == 128) a1 = A[(size_t)i * K + 64 + lane];
        float acc = 0.f;
#pragma unroll
        for (int k = 0; k < 64; ++k) acc = fmaf(rlanef(a0, k), wr[k], acc);
        if (K == 128) {
#pragma unroll
            for (int k = 0; k < 64; ++k) acc = fmaf(rlanef(a1, k), wr[64 + k], acc);
        }
        T[(size_t)i * 64 + lane] = acc * dinv[i];
    }
}

// ---------------- GCN aggregation ----------------
__global__ __launch_bounds__(256) void k_agg(const float* __restrict__ T,
                                             const int* __restrict__ rowptr,
                                             const int* __restrict__ csrc,
                                             const float* __restrict__ dinv,
                                             const float* __restrict__ bias,
                                             float* __restrict__ H, int n) {
    int lane = threadIdx.x & 63;
    int w = threadIdx.x >> 6;
    int nid = blockIdx.x * 4 + w;
    if (nid >= n) return;
    float dn = dinv[nid];
    float acc = T[(size_t)nid * 64 + lane];   // self loop (pre-scaled)
    int r0 = rowptr[nid], r1 = rowptr[nid + 1];
#pragma unroll 1
    for (int p0 = r0; p0 < r1; p0 += 64) {
        int m = r1 - p0; if (m > 64) m = 64;
        int sv = (lane < m) ? csrc[p0 + lane] : 0;
        if (m == 64) {
#pragma unroll
            for (int i = 0; i < 64; ++i) {
                int s = __builtin_amdgcn_readlane(sv, i);
                acc += T[(size_t)s * 64 + lane];
            }
        } else {
#pragma unroll 1
            for (int i = 0; i < m; ++i) {
                int s = __builtin_amdgcn_readlane(sv, i);
                acc += T[(size_t)s * 64 + lane];
            }
        }
    }
    H[(size_t)nid * 64 + lane] = fmaxf(fmaf(dn, acc, bias[lane]), 0.f);
}

// ---------------- edge MLP ----------------
// lane = edge. z[64] accumulators = 16 named float4s (guaranteed VGPRs).
// h streamed quad-by-quad from global (per-lane gather); weights read at
// wave-uniform addresses (const __restrict__, uniform control flow -> s_load).
// Stage 2 per-lane too (z is per-edge): 1024 fma, macro-unrolled. No LDS.

#define FMA4Q(zq, hs, wr, B) \
    zq.x = fmaf(hs, wr[(B) + 0], zq.x); \
    zq.y = fmaf(hs, wr[(B) + 1], zq.y); \
    zq.z = fmaf(hs, wr[(B) + 2], zq.z); \
    zq.w = fmaf(hs, wr[(B) + 3], zq.w);

#define ROWFMA(hs, krow) { \
    const float* wr = Wm1 + (size_t)(krow) * 64; \
    FMA4Q(z0, hs, wr, 0)   FMA4Q(z1, hs, wr, 4)   FMA4Q(z2, hs, wr, 8)   FMA4Q(z3, hs, wr, 12) \
    FMA4Q(z4, hs, wr, 16)  FMA4Q(z5, hs, wr, 20)  FMA4Q(z6, hs, wr, 24)  FMA4Q(z7, hs, wr, 28) \
    FMA4Q(z8, hs, wr, 32)  FMA4Q(z9, hs, wr, 36)  FMA4Q(z10, hs, wr, 40) FMA4Q(z11, hs, wr, 44) \
    FMA4Q(z12, hs, wr, 48) FMA4Q(z13, hs, wr, 52) FMA4Q(z14, hs, wr, 56) FMA4Q(z15, hs, wr, 60) }

#define RELU4(zq) \
    zq.x = fmaxf(zq.x, 0.f); zq.y = fmaxf(zq.y, 0.f); \
    zq.z = fmaxf(zq.z, 0.f); zq.w = fmaxf(zq.w, 0.f);

#define S2Q(zs, j) { \
    const float* w2 = Wm2 + (size_t)(j) * 16; \
    o0.x = fmaf(zs, w2[0],  o0.x);  o0.y = fmaf(zs, w2[1],  o0.y); \
    o0.z = fmaf(zs, w2[2],  o0.z);  o0.w = fmaf(zs, w2[3],  o0.w); \
    o1.x = fmaf(zs, w2[4],  o1.x);  o1.y = fmaf(zs, w2[5],  o1.y); \
    o1.z = fmaf(zs, w2[6],  o1.z);  o1.w = fmaf(zs, w2[7],  o1.w); \
    o2.x = fmaf(zs, w2[8],  o2.x);  o2.y = fmaf(zs, w2[9],  o2.y); \
    o2.z = fmaf(zs, w2[10], o2.z);  o2.w = fmaf(zs, w2[11], o2.w); \
    o3.x = fmaf(zs, w2[12], o3.x);  o3.y = fmaf(zs, w2[13], o3.y); \
    o3.z = fmaf(zs, w2[14], o3.z);  o3.w = fmaf(zs, w2[15], o3.w); }

__global__ __launch_bounds__(256, 4) void k_mlp(const float* __restrict__ H,
                                                const int* __restrict__ ei,
                                                const float* __restrict__ Wm1,  // [128][64]
                                                const float* __restrict__ bm1,
                                                const float* __restrict__ Wm2,  // [64][16]
                                                const float* __restrict__ bm2,
                                                float* __restrict__ out,
                                                int e) {
    int eid = blockIdx.x * 256 + threadIdx.x;
    bool ok = eid < e;
    int idx = ok ? eid : 0;
    int r = ei[idx];
    int c = ei[e + idx];

    const float4* b1q = (const float4*)bm1;
    float4 z0 = b1q[0],  z1 = b1q[1],  z2 = b1q[2],  z3 = b1q[3];
    float4 z4 = b1q[4],  z5 = b1q[5],  z6 = b1q[6],  z7 = b1q[7];
    float4 z8 = b1q[8],  z9 = b1q[9],  z10 = b1q[10], z11 = b1q[11];
    float4 z12 = b1q[12], z13 = b1q[13], z14 = b1q[14], z15 = b1q[15];

    const float4* hr4 = (const float4*)(H + (size_t)r * 64);
    const float4* hc4 = (const float4*)(H + (size_t)c * 64);

#pragma unroll 1
    for (int q = 0; q < 16; ++q) {
        float4 hv = hr4[q];
        int k = q * 4;
        ROWFMA(hv.x, k + 0)
        ROWFMA(hv.y, k + 1)
        ROWFMA(hv.z, k + 2)
        ROWFMA(hv.w, k + 3)
    }
#pragma unroll 1
    for (int q = 0; q < 16; ++q) {
        float4 hv = hc4[q];
        int k = 64 + q * 4;
        ROWFMA(hv.x, k + 0)
        ROWFMA(hv.y, k + 1)
        ROWFMA(hv.z, k + 2)
        ROWFMA(hv.w, k + 3)
    }

    RELU4(z0)  RELU4(z1)  RELU4(z2)  RELU4(z3)
    RELU4(z4)  RELU4(z5)  RELU4(z6)  RELU4(z7)
    RELU4(z8)  RELU4(z9)  RELU4(z10) RELU4(z11)
    RELU4(z12) RELU4(z13) RELU4(z14) RELU4(z15)

    const float4* b2q = (const float4*)bm2;
    float4 o0 = b2q[0], o1 = b2q[1], o2 = b2q[2], o3 = b2q[3];

    S2Q(z0.x, 0)   S2Q(z0.y, 1)   S2Q(z0.z, 2)   S2Q(z0.w, 3)
    S2Q(z1.x, 4)   S2Q(z1.y, 5)   S2Q(z1.z, 6)   S2Q(z1.w, 7)
    S2Q(z2.x, 8)   S2Q(z2.y, 9)   S2Q(z2.z, 10)  S2Q(z2.w, 11)
    S2Q(z3.x, 12)  S2Q(z3.y, 13)  S2Q(z3.z, 14)  S2Q(z3.w, 15)
    S2Q(z4.x, 16)  S2Q(z4.y, 17)  S2Q(z4.z, 18)  S2Q(z4.w, 19)
    S2Q(z5.x, 20)  S2Q(z5.y, 21)  S2Q(z5.z, 22)  S2Q(z5.w, 23)
    S2Q(z6.x, 24)  S2Q(z6.y, 25)  S2Q(z6.z, 26)  S2Q(z6.w, 27)
    S2Q(z7.x, 28)  S2Q(z7.y, 29)  S2Q(z7.z, 30)  S2Q(z7.w, 31)
    S2Q(z8.x, 32)  S2Q(z8.y, 33)  S2Q(z8.z, 34)  S2Q(z8.w, 35)
    S2Q(z9.x, 36)  S2Q(z9.y, 37)  S2Q(z9.z, 38)  S2Q(z9.w, 39)
    S2Q(z10.x, 40) S2Q(z10.y, 41) S2Q(z10.z, 42) S2Q(z10.w, 43)
    S2Q(z11.x, 44) S2Q(z11.y, 45) S2Q(z11.z, 46) S2Q(z11.w, 47)
    S2Q(z12.x, 48) S2Q(z12.y, 49) S2Q(z12.z, 50) S2Q(z12.w, 51)
    S2Q(z13.x, 52) S2Q(z13.y, 53) S2Q(z13.z, 54) S2Q(z13.w, 55)
    S2Q(z14.x, 56) S2Q(z14.y, 57) S2Q(z14.z, 58) S2Q(z14.w, 59)
    S2Q(z15.x, 60) S2Q(z15.y, 61) S2Q(z15.z, 62) S2Q(z15.w, 63)

    if (ok) {
        float4* op = (float4*)(out + (size_t)eid * 16);
        op[0] = o0; op[1] = o1; op[2] = o2; op[3] = o3;
    }
}

// ---------------- launch ----------------

extern "C" void kernel_launch(void* const* d_in, const int* in_sizes, int n_in,
                              void* d_out, int out_size, void* d_ws, size_t ws_size,
                              hipStream_t stream) {
    const float* x   = (const float*)d_in[0];
    const int*   ei  = (const int*)d_in[1];
    const float* W1  = (const float*)d_in[2];
    const float* b1  = (const float*)d_in[3];
    const float* W2  = (const float*)d_in[4];
    const float* b2  = (const float*)d_in[5];
    const float* Wm1 = (const float*)d_in[6];
    const float* bm1 = (const float*)d_in[7];
    const float* Wm2 = (const float*)d_in[8];
    const float* bm2 = (const float*)d_in[9];
    float* out = (float*)d_out;

    int n = in_sizes[0] / IN_C;       // 50000
    int e = in_sizes[1] / 2;          // 800000

    // workspace layout (all offsets kept 16B-aligned)
    char* w = (char*)d_ws;
    int* cnt    = (int*)w;                 w += (size_t)n * 4;
    int* tmp    = (int*)w;                 w += (size_t)n * 4;
    int* bsum   = (int*)w;                 w += 256 * 4;
    int* rowptr = (int*)w;                 w += (size_t)(n + 4) * 4;
    int* cur    = (int*)w;                 w += (size_t)n * 4;
    float* dinv = (float*)w;               w += (size_t)n * 4;
    int* csrc   = (int*)w;                 w += (size_t)e * 4;
    float* t    = (float*)w;               w += (size_t)n * HID * 4;
    float* h1   = (float*)w;               w += (size_t)n * HID * 4;
    float* h2   = (float*)w;               w += (size_t)n * HID * 4;

    int nb_n256 = (n + 255) / 256;
    int nb_e256 = (e + 255) / 256;
    int nb_scan = (n + 1023) / 1024;

    k_init_cnt<<<nb_n256, 256, 0, stream>>>(cnt, n);
    k_count<<<nb_e256, 256, 0, stream>>>(ei, cnt, e);
    k_scan1<<<nb_scan, 1024, 0, stream>>>(cnt, tmp, bsum, n);
    k_scan2<<<1, 64, 0, stream>>>(bsum, nb_scan);
    k_scan3<<<nb_n256, 256, 0, stream>>>(cnt, tmp, bsum, rowptr, cur, dinv, n, e);
    k_scatter<<<nb_e256, 256, 0, stream>>>(ei, cur, csrc, e);

    const int NPW = 8;                               // nodes per wave
    int nwaves = (n + NPW - 1) / NPW;
    int nb_gemm = (nwaves + 3) / 4;
    int nb_agg = (n + 3) / 4;
    // layer 1
    k_gemm_node<IN_C><<<nb_gemm, 256, 0, stream>>>(x, W1, dinv, t, n, NPW);
    k_agg<<<nb_agg, 256, 0, stream>>>(t, rowptr, csrc, dinv, b1, h1, n);
    // layer 2
    k_gemm_node<HID><<<nb_gemm, 256, 0, stream>>>(h1, W2, dinv, t, n, NPW);
    k_agg<<<nb_agg, 256, 0, stream>>>(t, rowptr, csrc, dinv, b2, h2, n);
    // edge MLP
    int nb_mlp = (e + 255) / 256;
    k_mlp<<<nb_mlp, 256, 0, stream>>>(h2, ei, Wm1, bm1, Wm2, bm2, out, e);
}